// Round 7
// baseline (164.352 us; speedup 1.0000x reference)
//
#include <hip/hip_runtime.h>

#define BATCH 512
#define SEQ   512
#define VOCAB 1000
#define EMB   100
#define UNITS 64

// 2*log2(e): exp(2y) = exp2(KSCALE*y); folded into P and Whh at load time.
#define KSCALE 2.885390081777926814f

typedef float v2f __attribute__((ext_vector_type(2)));
typedef float v4f __attribute__((ext_vector_type(4)));
typedef int   v2i __attribute__((ext_vector_type(2)));

// ---------------------------------------------------------------------------
// Kernel 1: P[v][u] = KSCALE * ( sum_d emb[v][d]*Wxh[d][u] + b[u] + colsum_u )
// colsum_u = sum_i Whh[i][u] comes from the scan's r-substitution
// (h = 1 - 2r  =>  sum_i h_i W_iu = colsum_u - 2 sum_i r_i W_iu).
// ---------------------------------------------------------------------------
__global__ __launch_bounds__(256) void proj_kernel(
    const float* __restrict__ emb, const float* __restrict__ Wxh,
    const float* __restrict__ bias, const float* __restrict__ Whh,
    float* __restrict__ P) {
  const int v = blockIdx.x * 4 + (threadIdx.x >> 6);
  const int u = threadIdx.x & 63;
  const float* e = emb + v * EMB;
  float a0 = 0.f, a1 = 0.f, a2 = 0.f, a3 = 0.f;
#pragma unroll
  for (int d = 0; d < EMB; d += 4) {
    a0 = fmaf(e[d + 0], Wxh[(d + 0) * UNITS + u], a0);
    a1 = fmaf(e[d + 1], Wxh[(d + 1) * UNITS + u], a1);
    a2 = fmaf(e[d + 2], Wxh[(d + 2) * UNITS + u], a2);
    a3 = fmaf(e[d + 3], Wxh[(d + 3) * UNITS + u], a3);
  }
  float cs = 0.f;
#pragma unroll
  for (int i = 0; i < UNITS; ++i) cs += Whh[i * UNITS + u];
  P[v * UNITS + u] = (((a0 + a1) + (a2 + a3)) + bias[u] + cs) * KSCALE;
}

// ---------------------------------------------------------------------------
// Kernel 2: sequential scan, FOUR waves per batch row (one block of 256).
//   r[j] <- rcp(exp2(P'[tok_t][j] - 2K sum_i r_i Whh[i][j]) + 1)   (r6 algebra)
//
// r6 post-mortem: single-wave step is pinned at ~492 cyc across every
// structure; only ~100 cyc is VALU issue -- the rest is h-distribution
// latency (LDS round trip or cross-lane hazard stalls) + 32 pk_fma of MAC
// issue that ONE wave must swallow. This version splits the matvec across
// 4 waves: wave w owns outputs j in [16w,16w+16), lane (g=l>>4, m=l&15)
// sums i in [16g,16g+16) for j=16w+m -> 8 pk_fma/lane, 4 staggered
// conflict-free ds_read_b128, K-merge via the self-pair swap trick
// (permlane32_swap(s,s)+add, permlane16_swap(u,u)+add; swap semantics
// verified by r1/r6 passing benches).
//
// Cross-wave recurrence: ping-pong LDS hb[2][64] with ONE raw s_barrier per
// step. NOT __syncthreads(): that drains vmcnt(0), putting the P-row
// prefetch's global latency on the chain. Manual `s_waitcnt lgkmcnt(0)`
// (write retired, reads returned) + __builtin_amdgcn_s_barrier() keeps the
// global prefetch in flight across the barrier (HK discipline, guide s5).
// Correctness: wave Y's reads of hb[par] complete before Y signals the
// barrier (lgkmcnt(0)); wave X writes hb[par^1] only; X's next-step write
// to hb[par] happens after the barrier all waves signed. No ordering
// assumption between waves beyond the barrier.
// ---------------------------------------------------------------------------
__global__ __launch_bounds__(256)
void scan_kernel(
    const int* __restrict__ tok, const float* __restrict__ P,
    const float* __restrict__ Whh, const float* __restrict__ Wout,
    const float* __restrict__ bout, float* __restrict__ out) {
  const int row  = blockIdx.x;
  const int tid  = threadIdx.x;
  const int lane = tid & 63;
  const int w    = tid >> 6;     // wave: owns outputs [16w, 16w+16)
  const int g    = lane >> 4;    // K-group: i in [16g, 16g+16)
  const int m    = lane & 15;
  const int j    = 16 * w + m;   // this thread's output column

  __shared__ __align__(16) float hb[2][UNITS];  // ping-pong r-state

  // Weights scaled by -2*KSCALE, in the staggered read order:
  //   read slot q covers i-block 16g + 4*((q+g)&3); pairs within block.
  v2f wv[8];
#pragma unroll
  for (int q = 0; q < 4; ++q) {
    const int rr = (q + g) & 3;
#pragma unroll
    for (int p = 0; p < 2; ++p) {
      const int i0 = 16 * g + 4 * rr + 2 * p;
      float ax = Whh[(i0 + 0) * UNITS + j] * (-2.f * KSCALE);
      float ay = Whh[(i0 + 1) * UNITS + j] * (-2.f * KSCALE);
      asm volatile("" : "+v"(ax), "+v"(ay));
      wv[2 * q + p].x = ax;
      wv[2 * q + p].y = ay;
    }
  }

  // All 512 tokens of this row, pre-scaled by UNITS (per-wave copy).
  int tokv[SEQ / 64];
  const int* trow = tok + (long)row * SEQ;
#pragma unroll
  for (int c = 0; c < SEQ / 64; ++c) {
    int t = trow[c * 64 + lane] * UNITS;
    asm volatile("" : "+v"(t));
    tokv[c] = t;
  }

  // r_0 = 0.5 (h_0 = 0).
  if (tid < UNITS) hb[0][tid] = 0.5f;
  __syncthreads();  // one-time full barrier (vmcnt drain harmless here)

  // Distance-1 P-row prefetch (value for step t loaded during step t-1).
  int tk0 = __builtin_amdgcn_readlane(tokv[0], 0);
  float a = P[(long)tk0 + j];

#pragma unroll
  for (int c = 0; c < SEQ / 64; ++c) {
#pragma unroll 2
    for (int tt = 0; tt < 64; ++tt) {
      const int par = tt & 1;  // c*64 is even -> global parity == tt&1
      float a_cur = a;
      // Prefetch next step's P row (tt==63 fetches a discarded valid addr;
      // corrected at the chunk boundary below).
      int tkn = __builtin_amdgcn_readlane(tokv[c], (tt + 1) & 63);
      a = P[(long)tkn + j];

      // ---- Read MY 16 r-values: 4x ds_read_b128, staggered => 0-conflict,
      //      16-way same-address broadcast within each (g,q) cohort. ----
      const v4f* hp = (const v4f*)hb[par];
      v4f hq[4];
#pragma unroll
      for (int q = 0; q < 4; ++q) hq[q] = hp[4 * g + ((q + g) & 3)];

      // ---- 16 MACs: 8 pk_fma in 2 chains of depth 4. ----
      v2f acc0, acc1;
#pragma unroll
      for (int q = 0; q < 4; ++q) {
        v2f lo = __builtin_shufflevector(hq[q], hq[q], 0, 1);
        v2f hi = __builtin_shufflevector(hq[q], hq[q], 2, 3);
        if (q == 0) {
          acc0 = lo * wv[0];
          acc1 = hi * wv[1];
        } else {
          acc0 += lo * wv[2 * q + 0];
          acc1 += hi * wv[2 * q + 1];
        }
      }
      v2f rr2 = acc0 + acc1;
      float s = rr2.x + rr2.y;  // partial of Ky[j] over i in [16g,16g+16)

      // ---- K-merge over the 4 g-groups (self-pair swap trick). ----
      v2i swA = __builtin_amdgcn_permlane32_swap(
          __float_as_int(s), __float_as_int(s), false, false);
      float u = __int_as_float(swA[0]) + __int_as_float(swA[1]);  // xor32
#if __has_builtin(__builtin_amdgcn_permlane16_swap)
      v2i swB = __builtin_amdgcn_permlane16_swap(
          __float_as_int(u), __float_as_int(u), false, false);
      float y = (__int_as_float(swB[0]) + __int_as_float(swB[1])) + a_cur;
#else
      float y = (u + __shfl_xor(u, 16)) + a_cur;
#endif

      // r = rcp(exp2(Ky)+1)  (h = 1-2r folded into weights/P).
      float ex = __builtin_amdgcn_exp2f(y);
      float r = __builtin_amdgcn_rcpf(ex + 1.f);

      // Publish to the other buffer; 4 g-cohort lanes write the same
      // address with the same value (benign).
      hb[par ^ 1][j] = r;

      // Raw barrier: retire LDS ops, do NOT drain vmcnt (prefetch lives).
      asm volatile("s_waitcnt lgkmcnt(0)" ::: "memory");
      __builtin_amdgcn_s_barrier();
    }
    if (c + 1 < SEQ / 64) {
      int tkb = __builtin_amdgcn_readlane(tokv[c + 1], 0);
      a = P[(long)tkb + j];
    }
  }

  // Final state: step 511 wrote hb[(511+1)&1] = hb[0]; last barrier done.
  float rv = hb[0][lane];
  float hT = fmaf(-2.f, rv, 1.f);
  float psum = hT * Wout[lane];
#pragma unroll
  for (int off = 32; off > 0; off >>= 1) psum += __shfl_xor(psum, off);
  if (tid == 0) out[row] = 1.f / (1.f + __expf(-(psum + bout[0])));
}

extern "C" void kernel_launch(void* const* d_in, const int* in_sizes, int n_in,
                              void* d_out, int out_size, void* d_ws, size_t ws_size,
                              hipStream_t stream) {
  const int*   tok  = (const int*)  d_in[0];  // [BATCH, SEQ] int32
  const float* emb  = (const float*)d_in[1];  // [VOCAB, EMB]
  const float* Wxh  = (const float*)d_in[2];  // [EMB, UNITS]
  const float* Whh  = (const float*)d_in[3];  // [UNITS, UNITS]
  const float* bias = (const float*)d_in[4];  // [UNITS]
  const float* Wout = (const float*)d_in[5];  // [UNITS, 1]
  const float* bout = (const float*)d_in[6];  // [1]
  float* out = (float*)d_out;                 // [BATCH, 1] fp32

  float* P = (float*)d_ws;                    // VOCAB*UNITS fp32 = 256 KB

  proj_kernel<<<VOCAB / 4, 256, 0, stream>>>(emb, Wxh, bias, Whh, P);
  scan_kernel<<<BATCH, 256, 0, stream>>>(tok, P, Whh, Wout, bout, out);
}